// Round 13
// baseline (29.395 us; speedup 1.0000x reference)
//
#include <hip/hip_runtime.h>
#include <math.h>

#define BB 1024   // batch (rows)
#define NN 64     // dims (cols)

#define LN2F 0.69314718055994530942f
#define BINS 256      // bins per unit interval
#define TW   64       // conv half-window in bins (3.27 sigma at h~0.0766)
#define HSIZE 769     // histogram bins over [-1,2]
#define NOUT 258      // output bins (abs bins 255..512)
#define OBASE 255

// Single kernel node (+ free blit memset of out):
//   blocks [0,256):   KNN — 4 query rows each; contribution atomicAdd'ed to out[0]
//   blocks [256,512): KDE — dim r, query chunk; contribution atomicAdd'ed to out[1+r]
// No cross-block handoff, no counters, no second kernel. out is zeroed by an
// in-graph memset node each replay; blocks accumulate with device-scope float
// atomicAdd (order noise ~1e-6 << 0.66 threshold).
__global__ __launch_bounds__(256, 4) void fused_kernel(const float* __restrict__ act,
                                                       const int* __restrict__ kptr,
                                                       float* __restrict__ out,
                                                       float joint_const_div_ln2) {
    const int bx = blockIdx.x;
    const int tid = threadIdx.x;

    __shared__ float s_d[4096];
    __shared__ float s_x[264];

    if (bx < 256) {
        // ---------------- KNN role: queries qbase..qbase+3 ----------------
        const int qbase = bx * 4;
        if (tid < 64) {
            ((float4*)s_x)[tid] = ((const float4*)(act + (size_t)qbase * NN))[tid];
        }
        __syncthreads();

        #pragma unroll 1
        for (int c = 0; c < 4; ++c) {
            const int j = tid + 256 * c;
            const float4* row = (const float4*)(act + (size_t)j * NN);
            float a0 = 0.f, a1 = 0.f, a2 = 0.f, a3 = 0.f;
            #pragma unroll 2
            for (int d = 0; d < 16; ++d) {
                const float4 v = row[d];
                {   const float4 qq = ((const float4*)s_x)[d];
                    float x0 = v.x - qq.x, x1 = v.y - qq.y, x2 = v.z - qq.z, x3 = v.w - qq.w;
                    a0 += x0 * x0 + x1 * x1 + x2 * x2 + x3 * x3; }
                {   const float4 qq = ((const float4*)s_x)[16 + d];
                    float x0 = v.x - qq.x, x1 = v.y - qq.y, x2 = v.z - qq.z, x3 = v.w - qq.w;
                    a1 += x0 * x0 + x1 * x1 + x2 * x2 + x3 * x3; }
                {   const float4 qq = ((const float4*)s_x)[32 + d];
                    float x0 = v.x - qq.x, x1 = v.y - qq.y, x2 = v.z - qq.z, x3 = v.w - qq.w;
                    a2 += x0 * x0 + x1 * x1 + x2 * x2 + x3 * x3; }
                {   const float4 qq = ((const float4*)s_x)[48 + d];
                    float x0 = v.x - qq.x, x1 = v.y - qq.y, x2 = v.z - qq.z, x3 = v.w - qq.w;
                    a3 += x0 * x0 + x1 * x1 + x2 * x2 + x3 * x3; }
            }
            s_d[0 * 1024 + j] = a0;
            s_d[1 * 1024 + j] = a1;
            s_d[2 * 1024 + j] = a2;
            s_d[3 * 1024 + j] = a3;
        }
        __syncthreads();

        // wave w handles query qbase+w
        const int w = tid >> 6, lane = tid & 63;
        float v[16];
        #pragma unroll
        for (int c = 0; c < 16; ++c) v[c] = s_d[w * 1024 + lane + 64 * c];
        const int kk = kptr[0];
        float last = 0.f;
        for (int e = 0; e <= kk; ++e) {
            float bv = 1e30f; int bi = 0;
            #pragma unroll
            for (int c = 0; c < 16; ++c) { if (v[c] < bv) { bv = v[c]; bi = c; } }
            float mv = bv; int mi = (lane << 4) | bi;
            #pragma unroll
            for (int off = 32; off > 0; off >>= 1) {
                float ov = __shfl_xor(mv, off);
                int   oi = __shfl_xor(mi, off);
                if (ov < mv || (ov == mv && oi < mi)) { mv = ov; mi = oi; }
            }
            last = mv;
            if ((mi >> 4) == lane) v[mi & 15] = 1e30f;
        }
        if (lane == 0) {
            s_x[256 + w] = __builtin_amdgcn_logf(fmaxf(last, 1e-12f)) * LN2F;  // ln(rho^2)
        }
        __syncthreads();

        if (tid == 0) {
            // out[0] contribution: (N/2) * mean(ln rho^2) / ln2 summed blockwise
            //   = sum4(ln rho^2) * (32/1024) / ln2
            float contrib = (s_x[256] + s_x[257] + s_x[258] + s_x[259])
                          * (0.03125f / LN2F);
            if (bx == 0) {
                // add -digamma(k)/ln2 + host-side constant once
                float dgk = -0.57721566490153286061f;                 // digamma(1)
                for (int t = 1; t < kk; ++t) dgk += 1.0f / (float)t;  // digamma(k)
                contrib += joint_const_div_ln2 - dgk * (1.0f / LN2F);
            }
            atomicAdd(&out[0], contrib);
        }
    } else {
        // ---------------- KDE role: dim r, query chunk ----------------
        const int idx = bx - 256;
        const int r = idx >> 2;        // 0..63
        const int chunk = idx & 3;     // 0..3 (256 queries each)

        int*   hint = (int*)s_d;       // [0,769) histogram (int counts)
        float* harr = s_d;             // same storage as float after convert
        float* ktab = s_d + 772;       // 65 floats
        float* outg = s_d + 840;       // 258 floats

        float cv[4];
        float lsum = 0.f, lsq = 0.f;
        #pragma unroll
        for (int c = 0; c < 4; ++c) {
            const int j = tid + 256 * c;
            float v = act[(size_t)j * NN + r];
            cv[c] = v;
            lsum += v; lsq += v * v;
        }
        #pragma unroll
        for (int off = 32; off > 0; off >>= 1) {
            lsum += __shfl_xor(lsum, off);
            lsq  += __shfl_xor(lsq,  off);
        }
        const int wid = tid >> 6;
        if ((tid & 63) == 0) { s_x[wid] = lsum; s_x[4 + wid] = lsq; }

        for (int i = tid; i < HSIZE; i += 256) hint[i] = 0;
        __syncthreads();

        const float total = s_x[0] + s_x[1] + s_x[2] + s_x[3];
        const float totsq = s_x[4] + s_x[5] + s_x[6] + s_x[7];
        const float mean = total * (1.f / BB);
        const float var = (totsq - (float)BB * mean * mean) * (1.f / (BB - 1)); // ddof=1
        const float stdv = sqrtf(fmaxf(var, 0.f));
        const float h = fmaxf(1.06f * 0.25f * stdv, 1e-4f);   // 1024^-0.2 = 0.25
        const float ih = 1.f / h;
        const float a  = 0.84932180028801904272f * ih;        // sqrt(0.5*log2 e)/h
        const float ad = a * (1.f / (float)BINS);

        #pragma unroll
        for (int c = 0; c < 4; ++c) {
            const float x = cv[c];
            int b0 = (int)floorf(x * (float)BINS) + BINS;             // p = x
            int b1 = (int)floorf(-x * (float)BINS) + BINS;            // p = -x
            int b2 = (int)floorf((2.f - x) * (float)BINS) + BINS;     // p = 2-x
            b0 = min(max(b0, 0), HSIZE - 1);
            b1 = min(max(b1, 0), HSIZE - 1);
            b2 = min(max(b2, 0), HSIZE - 1);
            atomicAdd(&hint[b0], 1);
            atomicAdd(&hint[b1], 1);
            atomicAdd(&hint[b2], 1);
        }
        if (tid <= TW) {
            const float t = ad * (float)tid;
            ktab[tid] = __builtin_amdgcn_exp2f(-(t * t));
        }
        __syncthreads();

        for (int i = tid; i < HSIZE; i += 256) {
            const int c = hint[i];
            harr[i] = (float)c;
        }
        __syncthreads();

        for (int o = tid; o < NOUT; o += 256) {
            const float* hp = harr + OBASE + o;
            float acc = hp[0] * ktab[0];
            #pragma unroll 4
            for (int m = 1; m <= TW; ++m)
                acc += (hp[m] + hp[-m]) * ktab[m];
            outg[o] = acc;
        }
        __syncthreads();

        const float dscale = 0.39894228040143267794f * ih * (1.f / (float)BB);
        const float x = cv[chunk];
        const float u = fmaf(x, (float)BINS, (float)OBASE + 0.5f);
        const float fu = floorf(u);
        const int i0 = (int)fu - OBASE;
        const float f = u - fu;
        const float dv = outg[i0] + (outg[i0 + 1] - outg[i0]) * f;
        float lp = __builtin_amdgcn_logf(fmaf(dv, dscale, 1e-8f)) * LN2F;

        #pragma unroll
        for (int off = 32; off > 0; off >>= 1) lp += __shfl_xor(lp, off);
        if ((tid & 63) == 0) s_x[8 + wid] = lp;
        __syncthreads();
        if (tid == 0) {
            const float p = s_x[8] + s_x[9] + s_x[10] + s_x[11];
            atomicAdd(&out[1 + r], -p * (1.0f / (float)BB));
        }
    }
}

extern "C" void kernel_launch(void* const* d_in, const int* in_sizes, int n_in,
                              void* d_out, int out_size, void* d_ws, size_t ws_size,
                              hipStream_t stream) {
    const float* act = (const float*)d_in[0];
    const int* kptr = (const int*)d_in[1];
    float* out = (float*)d_out;

    // host-side constants (pure arithmetic — capture safe)
    const double log_c_d = 0.5 * (double)NN * log(M_PI) - lgamma((double)NN / 2.0 + 1.0);
    const double xB = (double)BB;          // digamma(1024) via asymptotic series
    const double dg_B = log(xB) - 1.0 / (2.0 * xB) - 1.0 / (12.0 * xB * xB)
                        + 1.0 / (120.0 * xB * xB * xB * xB);
    // (dg_B + log_c_d)/ln2; the -digamma(k)/ln2 part is added on-device (k is device data)
    const float joint_const_div_ln2 = (float)((dg_B + log_c_d) / 0.69314718055994530942);

    hipMemsetAsync(out, 0, (size_t)out_size * sizeof(float), stream);  // blit node (~free)
    fused_kernel<<<512, 256, 0, stream>>>(act, kptr, out, joint_const_div_ln2);
}